// Round 2
// baseline (223.119 us; speedup 1.0000x reference)
//
#include <hip/hip_runtime.h>

typedef __bf16 bf16;
typedef __attribute__((ext_vector_type(8))) __bf16 bf16x8;
typedef __attribute__((ext_vector_type(4))) __bf16 bf16x4;
typedef __attribute__((ext_vector_type(4))) float f32x4;

#define MFMA16(A, B, C) __builtin_amdgcn_mfma_f32_16x16x32_bf16(A, B, C, 0, 0, 0)

static __device__ __forceinline__ void wave_lgkm_wait() {
  asm volatile("s_waitcnt lgkmcnt(0)" ::: "memory");
}

// ---------------------------------------------------------------------------
// k_prep: weight bf16 conversion, yu bilinear upsample, gating coefficients
// grid = 232 blocks x 256
// ---------------------------------------------------------------------------
__global__ __launch_bounds__(256) void k_prep(
    const float* __restrict__ y, const float* __restrict__ wy, const float* __restrict__ by,
    const float* __restrict__ wq, const float* __restrict__ bq,
    const float* __restrict__ wk, const float* __restrict__ bk,
    const float* __restrict__ wv,
    bf16* __restrict__ wq_bf, bf16* __restrict__ wk_bf, bf16* __restrict__ wv_bf,
    float* __restrict__ yu, float* __restrict__ aq, float* __restrict__ cq,
    float* __restrict__ ak, float* __restrict__ ck)
{
  int blk = blockIdx.x, t = threadIdx.x;
  if (blk < 192) {
    int idx4 = blk * 256 + t;
    int fo = idx4 * 4;
    const float* src; bf16* dst; int off;
    if (fo < 65536)       { src = wq; dst = wq_bf; off = fo; }
    else if (fo < 131072) { src = wk; dst = wk_bf; off = fo - 65536; }
    else                  { src = wv; dst = wv_bf; off = fo - 131072; }
    float4 v = *(const float4*)(src + off);
    bf16x4 o;
    o[0] = (bf16)v.x; o[1] = (bf16)v.y; o[2] = (bf16)v.z; o[3] = (bf16)v.w;
    *(bf16x4*)(dst + off) = o;
  } else if (blk < 200) {
    // bilinear upsample y[b,1,24,24] -> yu[b,96,96], half-pixel, edge clamp
    int b = blk - 192;
    const float* yb = y + b * 576;
#pragma unroll 1
    for (int i = 0; i < 36; ++i) {
      int e = t + i * 256;
      int oh = e / 96, ow = e % 96;
      float sh = oh * 0.25f - 0.375f;
      float sw = ow * 0.25f - 0.375f;
      int ih0 = (int)floorf(sh);
      int iw0 = (int)floorf(sw);
      float fh = sh - (float)ih0, fw = sw - (float)iw0;
      int ih0c = min(23, max(0, ih0)), ih1c = min(23, max(0, ih0 + 1));
      int iw0c = min(23, max(0, iw0)), iw1c = min(23, max(0, iw0 + 1));
      float v00 = yb[ih0c * 24 + iw0c], v01 = yb[ih0c * 24 + iw1c];
      float v10 = yb[ih1c * 24 + iw0c], v11 = yb[ih1c * 24 + iw1c];
      yu[b * 9216 + e] = (1.0f - fh) * ((1.0f - fw) * v00 + fw * v01)
                       + fh * ((1.0f - fw) * v10 + fw * v11);
    }
  } else {
    // gate coefficients: aq = wq*wy, cq = wq*by + bq (same for k)
    int ol = t >> 5, cl = t & 31;
    int o = (blk - 200) * 8 + ol;
    int c0 = cl * 8;
    float4 wy0 = *(const float4*)(wy + c0), wy1 = *(const float4*)(wy + c0 + 4);
    float4 by0 = *(const float4*)(by + c0), by1 = *(const float4*)(by + c0 + 4);
    float4 q0  = *(const float4*)(wq + o * 256 + c0), q1 = *(const float4*)(wq + o * 256 + c0 + 4);
    float4 k0  = *(const float4*)(wk + o * 256 + c0), k1 = *(const float4*)(wk + o * 256 + c0 + 4);
    float wyv[8] = {wy0.x, wy0.y, wy0.z, wy0.w, wy1.x, wy1.y, wy1.z, wy1.w};
    float byv[8] = {by0.x, by0.y, by0.z, by0.w, by1.x, by1.y, by1.z, by1.w};
    float qv[8]  = {q0.x, q0.y, q0.z, q0.w, q1.x, q1.y, q1.z, q1.w};
    float kv[8]  = {k0.x, k0.y, k0.z, k0.w, k1.x, k1.y, k1.z, k1.w};
    float saq = 0.f, scq = 0.f, sak = 0.f, sck = 0.f;
#pragma unroll
    for (int j = 0; j < 8; ++j) {
      saq += qv[j] * wyv[j]; scq += qv[j] * byv[j];
      sak += kv[j] * wyv[j]; sck += kv[j] * byv[j];
    }
#pragma unroll
    for (int s = 16; s >= 1; s >>= 1) {
      saq += __shfl_xor(saq, s, 32);
      scq += __shfl_xor(scq, s, 32);
      sak += __shfl_xor(sak, s, 32);
      sck += __shfl_xor(sck, s, 32);
    }
    if (cl == 0) {
      aq[o] = saq; cq[o] = scq + bq[o];
      ak[o] = sak; ck[o] = sck + bk[o];
    }
  }
}

// ---------------------------------------------------------------------------
// k_fused: one block of 1024 threads (16 waves, 4/SIMD) per (b,h) row.
// Each wave owns one 16-row o/d tile. All intermediates on-chip.
//   LDS: xs [96 w][264 c]       50688 B  (reused as vs [96 w][264 d])
//        ks [256 o][104 w]      53248 B  (per-wave q-stage aliases own region;
//                                         reused as f32 out-stage [128][100])
//        bounce 2 x 16x[16][40] 40960 B  (double-buffered, parity on dt)
//   Total 144896 B -> 1 block/CU, 16 waves = 4 waves/SIMD.
// R2 change: q+k+v projections fully fused into ONE pass over xs. The xs
// fragment used as MFMA-A for q/k is identical to the B-fragment v needs,
// so 6 ds_read_b128 + 3 global weight reads feed 18 MFMAs per kq step
// (removes another 48 ds_read_b128/wave vs R1). VGPR budget: 18 f32x4 accs
// (72) + A[6] (24) + 3 B (12) + misc ~= 120 <= 128 hard cap @ 1024 thr.
// ---------------------------------------------------------------------------
__global__ __launch_bounds__(1024, 1) void k_fused(
    const float* __restrict__ x, const float* __restrict__ yu,
    const bf16* __restrict__ wq_bf, const bf16* __restrict__ wk_bf, const bf16* __restrict__ wv_bf,
    const float* __restrict__ bq, const float* __restrict__ bk, const float* __restrict__ bv,
    const float* __restrict__ aq, const float* __restrict__ cq,
    const float* __restrict__ ak, const float* __restrict__ ck,
    float* __restrict__ out)
{
  __shared__ __align__(16) bf16 xs[96 * 264];             // 50688 B (-> vs)
  __shared__ __align__(16) bf16 ks[256 * 104];            // 53248 B (-> out stage)
  __shared__ __align__(16) bf16 bounce[2][16 * 16 * 40];  // 40960 B

  int pl = blockIdx.x;
  int b = pl / 96, h = pl % 96;
  int t = threadIdx.x;
  int wid = t >> 6, lane = t & 63;
  int l15 = lane & 15, g = lane >> 4;
  int otile = wid * 16;            // this wave's 16-row o/d tile base

  // ---- phase 0: load x[b,:,h,:] -> xs[w][c] (bf16) ----
  {
    const float* xrow = x + (size_t)b * 2359296 + (size_t)h * 96;
#pragma unroll
    for (int i = 0; i < 3; ++i) {
      int tsk = i * 1024 + t;       // 96 w x 32 cgroups
      int w = tsk % 96;
      int c0 = (tsk / 96) * 8;
      float v[8];
#pragma unroll
      for (int j = 0; j < 8; ++j) v[j] = xrow[(size_t)(c0 + j) * 9216 + w];
      bf16x8 o8;
#pragma unroll
      for (int j = 0; j < 8; ++j) o8[j] = (bf16)v[j];
      *(bf16x8*)(xs + w * 264 + c0) = o8;
    }
  }
  __syncthreads();

  const float SC = 0.17677669529663687f;  // 1/sqrt(32), folded into q
  bf16* stg = ks + otile * 104;           // q-stage aliases this wave's k region

  bf16x8 qf[3];   // this wave's 16 o-rows of q, A-fragment layout

  // ---- phase 1: q, k AND v projections in one pass over xs ----
  // Per kq: 6 LDS A-frags + 3 global weight frags -> 18 MFMAs.
  {
    f32x4 qacc[6] = {};
    f32x4 kacc[6] = {};
    f32x4 vacc[6] = {};
#pragma unroll 1
    for (int kq = 0; kq < 8; ++kq) {
      const bf16* xp = xs + kq * 32 + g * 8;
      bf16x8 A[6];
#pragma unroll
      for (int m = 0; m < 6; ++m)
        A[m] = *(const bf16x8*)(xp + (m * 16 + l15) * 264);
      size_t wo = (size_t)(otile + l15) * 256 + kq * 32 + g * 8;
      bf16x8 Bq = *(const bf16x8*)(wq_bf + wo);
      bf16x8 Bk = *(const bf16x8*)(wk_bf + wo);
      bf16x8 Bv = *(const bf16x8*)(wv_bf + wo);
#pragma unroll
      for (int m = 0; m < 6; ++m) {
        qacc[m] = MFMA16(A[m], Bq, qacc[m]);       // D[w][o]  (swapped)
        kacc[m] = MFMA16(A[m], Bk, kacc[m]);       // D[w][o]  (swapped)
        vacc[m] = MFMA16(Bv, A[m], vacc[m]);       // D[d][w]  (natural)
      }
    }

    // yu gate values loaded AFTER the MFMA loop (keeps loop VGPR pressure low)
    float4 yv[6];
    {
      const float* yr = yu + (size_t)pl * 96;
#pragma unroll
      for (int mt = 0; mt < 6; ++mt)
        yv[mt] = *(const float4*)(yr + mt * 16 + g * 4);
    }
    int o = otile + l15;
    float bqv = bq[o], aq0 = aq[o], cq0 = cq[o];
    float bkv = bk[o], ak0 = ak[o], ck0 = ck[o];

    // q: gate, scale, stage through own ks region -> qf regs (A-frag layout)
#pragma unroll
    for (int m = 0; m < 6; ++m) {
      float yy[4] = {yv[m].x, yv[m].y, yv[m].z, yv[m].w};
      bf16x4 pk;
#pragma unroll
      for (int r = 0; r < 4; ++r)
        pk[r] = (bf16)((qacc[m][r] + bqv) * (yy[r] * aq0 + cq0) * SC);
      *(bf16x4*)(stg + l15 * 104 + m * 16 + g * 4) = pk;
    }
    wave_lgkm_wait();
#pragma unroll
    for (int kk = 0; kk < 3; ++kk)
      qf[kk] = *(const bf16x8*)(stg + l15 * 104 + kk * 32 + g * 8);
    wave_lgkm_wait();   // qf reads landed before k overwrites this region

    // k: gate -> ks[o][w] (this wave's 16 rows)
#pragma unroll
    for (int m = 0; m < 6; ++m) {
      float yy[4] = {yv[m].x, yv[m].y, yv[m].z, yv[m].w};
      bf16x4 pk;
#pragma unroll
      for (int r = 0; r < 4; ++r)
        pk[r] = (bf16)((kacc[m][r] + bkv) * (yy[r] * ak0 + ck0));
      *(bf16x4*)(ks + (size_t)o * 104 + m * 16 + g * 4) = pk;
    }

    // v: bias; wait for ALL waves to finish reading xs, then write vs = xs
    float4 bm = *(const float4*)(bv + otile + g * 4);
    float bb[4] = {bm.x, bm.y, bm.z, bm.w};
    __syncthreads();   // all xs reads done block-wide (q-stage/k writes local)
    bf16* vs = xs;     // reuse xs as vs[w][264 d]
#pragma unroll
    for (int n = 0; n < 6; ++n) {
      bf16x4 pk;
#pragma unroll
      for (int r = 0; r < 4; ++r) pk[r] = (bf16)(vacc[n][r] + bb[r]);
      *(bf16x4*)(vs + (size_t)(n * 16 + l15) * 264 + otile + g * 4) = pk;
    }
  }
  __syncthreads();     // ks + vs visible to all waves

  // ---- phase 4: scores (q pre-scaled), exp, bounce (dbuf), out = P*v ----
  const bf16* vs = xs;
  f32x4 oacc[6] = {};
  float lp[4] = {0.f, 0.f, 0.f, 0.f};

#pragma unroll 1
  for (int dt = 0; dt < 8; ++dt) {
    int d0 = dt * 32;
    f32x4 s[2] = {};
    const bf16* kp = ks + (size_t)(d0 + l15) * 104 + g * 8;
    __builtin_amdgcn_s_setprio(1);
#pragma unroll
    for (int kk = 0; kk < 3; ++kk) {
#pragma unroll
      for (int dn = 0; dn < 2; ++dn) {
        bf16x8 B = *(const bf16x8*)(kp + (size_t)dn * 16 * 104 + kk * 32);
        s[dn] = MFMA16(qf[kk], B, s[dn]);
      }
    }
    __builtin_amdgcn_s_setprio(0);
    bf16* bnc = bounce[dt & 1] + wid * (16 * 40);
#pragma unroll
    for (int dn = 0; dn < 2; ++dn) {
#pragma unroll
      for (int r = 0; r < 4; ++r) {
        float e = __expf(s[dn][r]);
        lp[r] += e;
        bnc[(g * 4 + r) * 40 + dn * 16 + l15] = (bf16)e;
      }
    }
    wave_lgkm_wait();   // bounce writes visible before cross-lane read
    bf16x8 pa = *(const bf16x8*)(bnc + l15 * 40 + g * 8);
    const bf16* vp = vs + (size_t)l15 * 264 + d0 + g * 8;
    __builtin_amdgcn_s_setprio(1);
#pragma unroll
    for (int n = 0; n < 6; ++n) {
      bf16x8 Bv = *(const bf16x8*)(vp + (size_t)n * 16 * 264);
      oacc[n] = MFMA16(pa, Bv, oacc[n]);
    }
    __builtin_amdgcn_s_setprio(0);
    // no trailing WAR drain: buffer parity means this bounce region is not
    // rewritten until dt+2, and dt+1's pre-read drain retires our pa read.
  }

  // row-sum reduce across the 16 l15 lanes holding the same rows
  float inv[4];
#pragma unroll
  for (int r = 0; r < 4; ++r) {
    float v = lp[r];
    v += __shfl_xor(v, 1, 16);
    v += __shfl_xor(v, 2, 16);
    v += __shfl_xor(v, 4, 16);
    v += __shfl_xor(v, 8, 16);
    inv[r] = 1.0f / v;
  }

  // ---- epilogue: stage f32 rows in LDS (ks reuse), flush full 384B rows ----
  __syncthreads();                  // everyone done reading ks
  float* fst = (float*)ks;          // [128 rows][pitch 100] = 51200 B
  int s_hi = wid >> 3;
  int lr = (wid & 7) * 16;
  float* ob = out + (size_t)b * 2359296 + (size_t)h * 96;
#pragma unroll 1
  for (int s = 0; s < 2; ++s) {
    if (s_hi == s) {
#pragma unroll
      for (int n = 0; n < 6; ++n)
#pragma unroll
        for (int r = 0; r < 4; ++r)
          fst[(lr + g * 4 + r) * 100 + n * 16 + l15] = oacc[n][r] * inv[r];
    }
    __syncthreads();
    int ob0 = s * 128;
#pragma unroll
    for (int it = 0; it < 3; ++it) {
      int idx = it * 1024 + t;      // 0..3071 float4 chunks
      int row = idx / 24, col = idx - row * 24;
      float4 v4 = *(const float4*)(fst + row * 100 + col * 4);
      *(float4*)(ob + (size_t)(ob0 + row) * 9216 + col * 4) = v4;
    }
    __syncthreads();
  }
}

// ---------------------------------------------------------------------------
extern "C" void kernel_launch(void* const* d_in, const int* in_sizes, int n_in,
                              void* d_out, int out_size, void* d_ws, size_t ws_size,
                              hipStream_t stream) {
  const float* x  = (const float*)d_in[0];
  const float* y  = (const float*)d_in[1];
  const float* wy = (const float*)d_in[2];
  const float* by = (const float*)d_in[3];
  const float* wq = (const float*)d_in[4];
  const float* bq = (const float*)d_in[5];
  const float* wk = (const float*)d_in[6];
  const float* bk = (const float*)d_in[7];
  const float* wv = (const float*)d_in[8];
  const float* bv = (const float*)d_in[9];
  float* out = (float*)d_out;

  char* wsb = (char*)d_ws;
  bf16* wq_bf = (bf16*)(wsb);
  bf16* wk_bf = (bf16*)(wsb + 131072);
  bf16* wv_bf = (bf16*)(wsb + 262144);
  float* yu   = (float*)(wsb + 393216);
  float* aq   = (float*)(wsb + 688128);
  float* cq   = (float*)(wsb + 689152);
  float* ak   = (float*)(wsb + 690176);
  float* ck   = (float*)(wsb + 691200);

  hipLaunchKernelGGL(k_prep, dim3(232), dim3(256), 0, stream,
                     y, wy, by, wq, bq, wk, bk, wv,
                     wq_bf, wk_bf, wv_bf, yu, aq, cq, ak, ck);
  hipLaunchKernelGGL(k_fused, dim3(768), dim3(1024), 0, stream,
                     x, yu, wq_bf, wk_bf, wv_bf, bq, bk, bv,
                     aq, cq, ak, ck, out);
}

// Round 3
// 216.116 us; speedup vs baseline: 1.0324x; 1.0324x over previous
//
#include <hip/hip_runtime.h>

typedef __bf16 bf16;
typedef __attribute__((ext_vector_type(8))) __bf16 bf16x8;
typedef __attribute__((ext_vector_type(4))) __bf16 bf16x4;
typedef __attribute__((ext_vector_type(4))) float f32x4;

#define MFMA16(A, B, C) __builtin_amdgcn_mfma_f32_16x16x32_bf16(A, B, C, 0, 0, 0)

static __device__ __forceinline__ void wave_lgkm_wait() {
  asm volatile("s_waitcnt lgkmcnt(0)" ::: "memory");
}

// ---------------------------------------------------------------------------
// k_prep: weight bf16 conversion, yu bilinear upsample, gating coefficients
// grid = 232 blocks x 256
// ---------------------------------------------------------------------------
__global__ __launch_bounds__(256) void k_prep(
    const float* __restrict__ y, const float* __restrict__ wy, const float* __restrict__ by,
    const float* __restrict__ wq, const float* __restrict__ bq,
    const float* __restrict__ wk, const float* __restrict__ bk,
    const float* __restrict__ wv,
    bf16* __restrict__ wq_bf, bf16* __restrict__ wk_bf, bf16* __restrict__ wv_bf,
    float* __restrict__ yu, float* __restrict__ aq, float* __restrict__ cq,
    float* __restrict__ ak, float* __restrict__ ck)
{
  int blk = blockIdx.x, t = threadIdx.x;
  if (blk < 192) {
    int idx4 = blk * 256 + t;
    int fo = idx4 * 4;
    const float* src; bf16* dst; int off;
    if (fo < 65536)       { src = wq; dst = wq_bf; off = fo; }
    else if (fo < 131072) { src = wk; dst = wk_bf; off = fo - 65536; }
    else                  { src = wv; dst = wv_bf; off = fo - 131072; }
    float4 v = *(const float4*)(src + off);
    bf16x4 o;
    o[0] = (bf16)v.x; o[1] = (bf16)v.y; o[2] = (bf16)v.z; o[3] = (bf16)v.w;
    *(bf16x4*)(dst + off) = o;
  } else if (blk < 200) {
    // bilinear upsample y[b,1,24,24] -> yu[b,96,96], half-pixel, edge clamp
    int b = blk - 192;
    const float* yb = y + b * 576;
#pragma unroll 1
    for (int i = 0; i < 36; ++i) {
      int e = t + i * 256;
      int oh = e / 96, ow = e % 96;
      float sh = oh * 0.25f - 0.375f;
      float sw = ow * 0.25f - 0.375f;
      int ih0 = (int)floorf(sh);
      int iw0 = (int)floorf(sw);
      float fh = sh - (float)ih0, fw = sw - (float)iw0;
      int ih0c = min(23, max(0, ih0)), ih1c = min(23, max(0, ih0 + 1));
      int iw0c = min(23, max(0, iw0)), iw1c = min(23, max(0, iw0 + 1));
      float v00 = yb[ih0c * 24 + iw0c], v01 = yb[ih0c * 24 + iw1c];
      float v10 = yb[ih1c * 24 + iw0c], v11 = yb[ih1c * 24 + iw1c];
      yu[b * 9216 + e] = (1.0f - fh) * ((1.0f - fw) * v00 + fw * v01)
                       + fh * ((1.0f - fw) * v10 + fw * v11);
    }
  } else {
    // gate coefficients: aq = wq*wy, cq = wq*by + bq (same for k)
    int ol = t >> 5, cl = t & 31;
    int o = (blk - 200) * 8 + ol;
    int c0 = cl * 8;
    float4 wy0 = *(const float4*)(wy + c0), wy1 = *(const float4*)(wy + c0 + 4);
    float4 by0 = *(const float4*)(by + c0), by1 = *(const float4*)(by + c0 + 4);
    float4 q0  = *(const float4*)(wq + o * 256 + c0), q1 = *(const float4*)(wq + o * 256 + c0 + 4);
    float4 k0  = *(const float4*)(wk + o * 256 + c0), k1 = *(const float4*)(wk + o * 256 + c0 + 4);
    float wyv[8] = {wy0.x, wy0.y, wy0.z, wy0.w, wy1.x, wy1.y, wy1.z, wy1.w};
    float byv[8] = {by0.x, by0.y, by0.z, by0.w, by1.x, by1.y, by1.z, by1.w};
    float qv[8]  = {q0.x, q0.y, q0.z, q0.w, q1.x, q1.y, q1.z, q1.w};
    float kv[8]  = {k0.x, k0.y, k0.z, k0.w, k1.x, k1.y, k1.z, k1.w};
    float saq = 0.f, scq = 0.f, sak = 0.f, sck = 0.f;
#pragma unroll
    for (int j = 0; j < 8; ++j) {
      saq += qv[j] * wyv[j]; scq += qv[j] * byv[j];
      sak += kv[j] * wyv[j]; sck += kv[j] * byv[j];
    }
#pragma unroll
    for (int s = 16; s >= 1; s >>= 1) {
      saq += __shfl_xor(saq, s, 32);
      scq += __shfl_xor(scq, s, 32);
      sak += __shfl_xor(sak, s, 32);
      sck += __shfl_xor(sck, s, 32);
    }
    if (cl == 0) {
      aq[o] = saq; cq[o] = scq + bq[o];
      ak[o] = sak; ck[o] = sck + bk[o];
    }
  }
}

// ---------------------------------------------------------------------------
// k_fused: one block of 1024 threads (16 waves, 4/SIMD) per (b,h) row.
// Each wave owns one 16-row o/d tile. All intermediates on-chip.
//   LDS: xs [96 w][264 c]   50688 B  (reused as vs [96 w][264 d], d-permuted)
//        ks [256 o][104 w]  53248 B  (per-wave q-stage aliases own region;
//                                     reused as f32 out-stage [128][100])
//   Total 103936 B -> 1 block/CU, 16 waves = 4 waves/SIMD.
// R3: swapped-QK (s = MFMA(K,Q) -> lane holds a full row-slice of P), V stored
// d-permuted so exp'd P is DIRECTLY the PV A-fragment: bounce buffer, its
// 64 writes + 8 reads and 16 lgkm drains per wave are gone. K-fragments
// double-buffered in registers (prefetch dt+1 before QK cluster).
// ---------------------------------------------------------------------------
__global__ __launch_bounds__(1024, 1) void k_fused(
    const float* __restrict__ x, const float* __restrict__ yu,
    const bf16* __restrict__ wq_bf, const bf16* __restrict__ wk_bf, const bf16* __restrict__ wv_bf,
    const float* __restrict__ bq, const float* __restrict__ bk, const float* __restrict__ bv,
    const float* __restrict__ aq, const float* __restrict__ cq,
    const float* __restrict__ ak, const float* __restrict__ ck,
    float* __restrict__ out)
{
  __shared__ __align__(16) bf16 xs[96 * 264];             // 50688 B (-> vs)
  __shared__ __align__(16) bf16 ks[256 * 104];            // 53248 B (-> out stage)

  int pl = blockIdx.x;
  int b = pl / 96, h = pl % 96;
  int t = threadIdx.x;
  int wid = t >> 6, lane = t & 63;
  int l15 = lane & 15, g = lane >> 4;
  int otile = wid * 16;            // this wave's 16-row o/d tile base

  // ---- phase 0: load x[b,:,h,:] -> xs[w][c] (bf16) ----
  {
    const float* xrow = x + (size_t)b * 2359296 + (size_t)h * 96;
#pragma unroll
    for (int i = 0; i < 3; ++i) {
      int tsk = i * 1024 + t;       // 96 w x 32 cgroups
      int w = tsk % 96;
      int c0 = (tsk / 96) * 8;
      float v[8];
#pragma unroll
      for (int j = 0; j < 8; ++j) v[j] = xrow[(size_t)(c0 + j) * 9216 + w];
      bf16x8 o8;
#pragma unroll
      for (int j = 0; j < 8; ++j) o8[j] = (bf16)v[j];
      *(bf16x8*)(xs + w * 264 + c0) = o8;
    }
  }
  __syncthreads();

  const float SC = 0.17677669529663687f;  // 1/sqrt(32), folded into q
  bf16* stg = ks + otile * 104;           // q-stage aliases this wave's k region

  bf16x8 qf[3];   // this wave's 16 o-rows of q, A-fragment layout

  // ---- phase 1: q, k AND v projections in one pass over xs ----
  // Per kq: 6 LDS A-frags + 3 global weight frags -> 18 MFMAs.
  {
    f32x4 qacc[6] = {};
    f32x4 kacc[6] = {};
    f32x4 vacc[6] = {};
#pragma unroll 1
    for (int kq = 0; kq < 8; ++kq) {
      const bf16* xp = xs + kq * 32 + g * 8;
      bf16x8 A[6];
#pragma unroll
      for (int m = 0; m < 6; ++m)
        A[m] = *(const bf16x8*)(xp + (m * 16 + l15) * 264);
      size_t wo = (size_t)(otile + l15) * 256 + kq * 32 + g * 8;
      bf16x8 Bq = *(const bf16x8*)(wq_bf + wo);
      bf16x8 Bk = *(const bf16x8*)(wk_bf + wo);
      bf16x8 Bv = *(const bf16x8*)(wv_bf + wo);
#pragma unroll
      for (int m = 0; m < 6; ++m) {
        qacc[m] = MFMA16(A[m], Bq, qacc[m]);       // D[w][o]  (swapped)
        kacc[m] = MFMA16(A[m], Bk, kacc[m]);       // D[w][o]  (swapped)
        vacc[m] = MFMA16(Bv, A[m], vacc[m]);       // D[d][w]  (natural)
      }
    }

    // yu gate values loaded AFTER the MFMA loop (keeps loop VGPR pressure low)
    float4 yv[6];
    {
      const float* yr = yu + (size_t)pl * 96;
#pragma unroll
      for (int mt = 0; mt < 6; ++mt)
        yv[mt] = *(const float4*)(yr + mt * 16 + g * 4);
    }
    int o = otile + l15;
    float bqv = bq[o], aq0 = aq[o], cq0 = cq[o];
    float bkv = bk[o], ak0 = ak[o], ck0 = ck[o];

    // q: gate, scale, stage through own ks region -> qf regs (A-frag layout)
#pragma unroll
    for (int m = 0; m < 6; ++m) {
      float yy[4] = {yv[m].x, yv[m].y, yv[m].z, yv[m].w};
      bf16x4 pk;
#pragma unroll
      for (int r = 0; r < 4; ++r)
        pk[r] = (bf16)((qacc[m][r] + bqv) * (yy[r] * aq0 + cq0) * SC);
      *(bf16x4*)(stg + l15 * 104 + m * 16 + g * 4) = pk;
    }
    wave_lgkm_wait();
#pragma unroll
    for (int kk = 0; kk < 3; ++kk)
      qf[kk] = *(const bf16x8*)(stg + l15 * 104 + kk * 32 + g * 8);
    wave_lgkm_wait();   // qf reads landed before k overwrites this region

    // k: gate -> ks[o][w] (this wave's 16 rows)
#pragma unroll
    for (int m = 0; m < 6; ++m) {
      float yy[4] = {yv[m].x, yv[m].y, yv[m].z, yv[m].w};
      bf16x4 pk;
#pragma unroll
      for (int r = 0; r < 4; ++r)
        pk[r] = (bf16)((kacc[m][r] + bkv) * (yy[r] * ak0 + ck0));
      *(bf16x4*)(ks + (size_t)o * 104 + m * 16 + g * 4) = pk;
    }

    // v: bias; wait for ALL waves to finish reading xs, then write vs = xs.
    // D-PERMUTED store: within each 32-d block, d = 32a + dn*16 + g*4 + r is
    // placed at pos = 32a + g*8 + dn*4 + r, so that the PV A-fragment is the
    // lane's own exp'd scores with no cross-lane traffic (k-map agreement).
    float4 bm = *(const float4*)(bv + otile + g * 4);
    float bb[4] = {bm.x, bm.y, bm.z, bm.w};
    __syncthreads();   // all xs reads done block-wide (q-stage/k writes local)
    bf16* vs = xs;     // reuse xs as vs[w][264 dpos]
    int vbase = (otile & ~16) + ((otile >> 2) & 4);   // 32a + dn*4
#pragma unroll
    for (int n = 0; n < 6; ++n) {
      bf16x4 pk;
#pragma unroll
      for (int r = 0; r < 4; ++r) pk[r] = (bf16)(vacc[n][r] + bb[r]);
      *(bf16x4*)(vs + (size_t)(n * 16 + l15) * 264 + vbase + g * 8) = pk;
    }
  }
  __syncthreads();     // ks + vs visible to all waves

  // ---- phase 4: swapped scores -> in-register P -> out = P*v ----
  const bf16* vs = xs;
  f32x4 oacc[6] = {};
  float lp = 0.f;

  bf16x8 KA[6], KB[6];   // K-fragment double-buffer (regs)
  {
    const bf16* kp = ks + (size_t)l15 * 104 + g * 8;
#pragma unroll
    for (int kk = 0; kk < 3; ++kk)
#pragma unroll
      for (int dn = 0; dn < 2; ++dn)
        KA[kk * 2 + dn] = *(const bf16x8*)(kp + (size_t)(dn * 16) * 104 + kk * 32);
  }

  auto attn_step = [&](int dt, bf16x8* Kc, bf16x8* Kn, bool pf) {
    int d0 = dt * 32;
    // prefetch next dt's K-fragments (independent; overlaps QK+exp+PV)
    if (pf) {
      const bf16* kp = ks + (size_t)((dt + 1) * 32 + l15) * 104 + g * 8;
#pragma unroll
      for (int kk = 0; kk < 3; ++kk)
#pragma unroll
        for (int dn = 0; dn < 2; ++dn)
          Kn[kk * 2 + dn] = *(const bf16x8*)(kp + (size_t)(dn * 16) * 104 + kk * 32);
    }
    f32x4 s0 = {}, s1 = {};
    __builtin_amdgcn_s_setprio(1);
#pragma unroll
    for (int kk = 0; kk < 3; ++kk) {
      s0 = MFMA16(Kc[kk * 2 + 0], qf[kk], s0);   // D[m=d][n=o]
      s1 = MFMA16(Kc[kk * 2 + 1], qf[kk], s1);
    }
    __builtin_amdgcn_s_setprio(0);
    // lane holds P[o=otile+l15][d0 + dn*16 + g*4 + r] -> pa slot j = dn*4+r
    bf16x8 pa;
#pragma unroll
    for (int r = 0; r < 4; ++r) {
      float e0 = __expf(s0[r]);
      float e1 = __expf(s1[r]);
      lp += e0 + e1;
      pa[r] = (bf16)e0;
      pa[4 + r] = (bf16)e1;
    }
    const bf16* vp = vs + (size_t)l15 * 264 + d0 + g * 8;
    __builtin_amdgcn_s_setprio(1);
#pragma unroll
    for (int n = 0; n < 6; ++n) {
      bf16x8 Bv = *(const bf16x8*)(vp + (size_t)n * 16 * 264);
      oacc[n] = MFMA16(pa, Bv, oacc[n]);
    }
    __builtin_amdgcn_s_setprio(0);
  };

#pragma unroll 1
  for (int dt2 = 0; dt2 < 4; ++dt2) {
    attn_step(2 * dt2,     KA, KB, true);
    attn_step(2 * dt2 + 1, KB, KA, 2 * dt2 + 1 < 7);
  }

  // row-sum: lane's lp is a partial for row o = otile+l15; sum across g-groups
  float vsum = lp;
  vsum += __shfl_xor(vsum, 16, 64);
  vsum += __shfl_xor(vsum, 32, 64);
  float inv = 1.0f / vsum;
  // redistribute to D-layout rows: epilogue needs inv of row otile + g*4 + r
  float invr[4];
#pragma unroll
  for (int r = 0; r < 4; ++r)
    invr[r] = __shfl(inv, g * 4 + r, 16);

  // ---- epilogue: stage f32 rows in LDS (ks reuse), flush full 384B rows ----
  __syncthreads();                  // everyone done reading ks
  float* fst = (float*)ks;          // [128 rows][pitch 100] = 51200 B
  int s_hi = wid >> 3;
  int lr = (wid & 7) * 16;
  float* ob = out + (size_t)b * 2359296 + (size_t)h * 96;
#pragma unroll 1
  for (int s = 0; s < 2; ++s) {
    if (s_hi == s) {
#pragma unroll
      for (int n = 0; n < 6; ++n)
#pragma unroll
        for (int r = 0; r < 4; ++r)
          fst[(lr + g * 4 + r) * 100 + n * 16 + l15] = oacc[n][r] * invr[r];
    }
    __syncthreads();
    int ob0 = s * 128;
#pragma unroll
    for (int it = 0; it < 3; ++it) {
      int idx = it * 1024 + t;      // 0..3071 float4 chunks
      int row = idx / 24, col = idx - row * 24;
      float4 v4 = *(const float4*)(fst + row * 100 + col * 4);
      *(float4*)(ob + (size_t)(ob0 + row) * 9216 + col * 4) = v4;
    }
    __syncthreads();
  }
}

// ---------------------------------------------------------------------------
extern "C" void kernel_launch(void* const* d_in, const int* in_sizes, int n_in,
                              void* d_out, int out_size, void* d_ws, size_t ws_size,
                              hipStream_t stream) {
  const float* x  = (const float*)d_in[0];
  const float* y  = (const float*)d_in[1];
  const float* wy = (const float*)d_in[2];
  const float* by = (const float*)d_in[3];
  const float* wq = (const float*)d_in[4];
  const float* bq = (const float*)d_in[5];
  const float* wk = (const float*)d_in[6];
  const float* bk = (const float*)d_in[7];
  const float* wv = (const float*)d_in[8];
  const float* bv = (const float*)d_in[9];
  float* out = (float*)d_out;

  char* wsb = (char*)d_ws;
  bf16* wq_bf = (bf16*)(wsb);
  bf16* wk_bf = (bf16*)(wsb + 131072);
  bf16* wv_bf = (bf16*)(wsb + 262144);
  float* yu   = (float*)(wsb + 393216);
  float* aq   = (float*)(wsb + 688128);
  float* cq   = (float*)(wsb + 689152);
  float* ak   = (float*)(wsb + 690176);
  float* ck   = (float*)(wsb + 691200);

  hipLaunchKernelGGL(k_prep, dim3(232), dim3(256), 0, stream,
                     y, wy, by, wq, bq, wk, bk, wv,
                     wq_bf, wk_bf, wv_bf, yu, aq, cq, ak, ck);
  hipLaunchKernelGGL(k_fused, dim3(768), dim3(1024), 0, stream,
                     x, yu, wq_bf, wk_bf, wv_bf, bq, bk, bv,
                     aq, cq, ak, ck, out);
}